// Round 6
// baseline (405.439 us; speedup 1.0000x reference)
//
#include <hip/hip_runtime.h>
#include <math.h>

#define S_LEN 4096
#define B_SZ  64
#define D_SZ  64
#define N_SZ  128
#define L_SZ  2
#define NSIG  32000

#define TILE   128
#define NT     (S_LEN / TILE)     // 32
#define GRP    16                 // consumer prefetch group
#define PWAVES 4
#define PSTEPS (TILE / PWAVES)    // 32 steps per producer wave per tile

// f32-rounded constants matching jnp.float32(...)
#define PHI_F     1.6180339887498949f
#define TWO_PI_F  6.2831853071795862f
#define INV_PI_F  0.31830988618379067f
#define SQ2_I2PI  0.22507907903927651f   // sqrt(2) / (2*pi)

// ---------------------------------------------------------------------------
// Phase 1+2 fused: producer/consumer scan, then the two resonant layers run
// in-block on the final state.  grid = B (64 blocks), block = 320 threads
// (wave 0 = consumer, waves 1..4 = producers).
//
// Scan recurrence (revolutions): q = fma(u, A, C); u = v_sin(q), with
// u = (hr+hi)/sqrt2, q = psi/(2pi) + 1/8, A = sqrt2/(2pi*(1+|w|)),
// C = (b*INV_PI) + t2, t2 = fmodf(t*PHI,2pi)*INV_PI + 0.125.
// All per-step values are BIT-IDENTICAL to the round-5 passing kernel:
// same rcp instruction, same mul-then-add order (asm barrier stops fp
// contraction), same s_t2 table.  Round-4 lesson: never perturb scan
// arithmetic while changing schedule.
// ---------------------------------------------------------------------------
__global__ __launch_bounds__(PWAVES * 64 + 64, 1) void scan_fused(
    const int*   __restrict__ ids,
    const float* __restrict__ emb,      // raw [V][128]
    const float* __restrict__ win_r,    // [L][D][N]
    const float* __restrict__ win_i,
    const float* __restrict__ wout_r,   // [L][N][D]
    const float* __restrict__ wout_i,
    const float* __restrict__ lw,       // [L][N]
    const float* __restrict__ lb,
    float2*      __restrict__ xft)      // [d][b] for the projection kernel
{
    __shared__ float  s_t2[S_LEN];                // 16 KB: tau/pi + 0.125
    __shared__ float2 sAC[2][TILE][D_SZ];         // 128 KB double buffer
    __shared__ float  s_xr[D_SZ], s_xi[D_SZ];
    __shared__ float  s_vr[N_SZ], s_vi[N_SZ];

    const int b    = blockIdx.x;
    const int tidx = threadIdx.x;
    const int wv   = tidx >> 6;        // 0 = consumer, 1..4 = producers
    const int lane = tidx & 63;        // = d

    const int* __restrict__ ids_b = ids + b * S_LEN;

    for (int i = tidx; i < S_LEN; i += (PWAVES + 1) * 64)
        s_t2[i] = fmodf((float)i * PHI_F, TWO_PI_F) * INV_PI_F + 0.125f;
    __syncthreads();

// producer: fill strip of tile TLE into buffer BUF (transform folded in;
// values bit-identical to the round-5 transform+XF path)
#define FILL(BUF, TLE) do {                                                  \
    const int t0_ = (TLE) * TILE + (wv - 1) * PSTEPS;                        \
    const int s0_ = (wv - 1) * PSTEPS;                                       \
    _Pragma("unroll")                                                        \
    for (int jj = 0; jj < PSTEPS; ++jj) {                                    \
        int   row_ = ids_b[t0_ + jj] << 7;                                   \
        float t2_  = s_t2[t0_ + jj];                                         \
        float w_   = emb[row_ + lane];                                       \
        float bb_  = emb[row_ + 64 + lane];                                  \
        float A_   = SQ2_I2PI * __builtin_amdgcn_rcpf(1.0f + fabsf(w_));     \
        float bm_  = bb_ * INV_PI_F;                                         \
        asm volatile("" : "+v"(bm_));   /* block fma-contraction */          \
        float C_   = bm_ + t2_;                                              \
        sAC[BUF][s0_ + jj][lane] = make_float2(A_, C_);                      \
    }                                                                        \
} while (0)

// consumer: 16-step register groups, ping-pong so ds_read latency hides
// under the previous group's fma->v_sin chain
#define LOADG(R, BUF, G) do {                                                \
    _Pragma("unroll")                                                        \
    for (int j = 0; j < GRP; ++j) R[j] = sAC[BUF][(G) * GRP + j][lane];      \
} while (0)

#define COMPG(R) do {                                                        \
    _Pragma("unroll")                                                        \
    for (int j = 0; j < GRP; ++j) {                                          \
        q = fmaf(u, R[j].x, R[j].y);                                         \
        u = __builtin_amdgcn_sinf(q);                                        \
    }                                                                        \
} while (0)

#define CONSUME(BUF) do {                                                    \
    float2 rA[GRP], rB[GRP];                                                 \
    LOADG(rA, BUF, 0);                                                       \
    __builtin_amdgcn_s_setprio(1);                                           \
    LOADG(rB, BUF, 1); COMPG(rA);                                            \
    LOADG(rA, BUF, 2); COMPG(rB);                                            \
    LOADG(rB, BUF, 3); COMPG(rA);                                            \
    LOADG(rA, BUF, 4); COMPG(rB);                                            \
    LOADG(rB, BUF, 5); COMPG(rA);                                            \
    LOADG(rA, BUF, 6); COMPG(rB);                                            \
    LOADG(rB, BUF, 7); COMPG(rA);                                            \
    COMPG(rB);                                                               \
    __builtin_amdgcn_s_setprio(0);                                           \
} while (0)

    float u = 0.0f, q = 0.0f;

    if (wv > 0) FILL(0, 0);
    __syncthreads();

    for (int t = 0; t < NT; ++t) {
        const int cur = t & 1;
        if (wv > 0) {
            if (t + 1 < NT) FILL(cur ^ 1, t + 1);
        } else {
            CONSUME(cur);
        }
        __syncthreads();
    }

    // ---- stage final state for the in-block layers ----
    if (wv == 0) {
        float pr = q - 0.125f;    // = psi_final / (2*pi), revolutions
        s_xr[lane] = __builtin_amdgcn_cosf(pr);
        s_xi[lane] = __builtin_amdgcn_sinf(pr);
    }
    __syncthreads();

    // ---- the two resonant layers (formulas verbatim from layers_kernel) ----
    const float t_last = (float)(4095.0 * 1.618033988749895);
    const float t_wrap = fmodf(t_last, TWO_PI_F);
    const int   n      = tidx;

    for (int l = 0; l < L_SZ; ++l) {
        if (n < N_SZ) {
            float ur = 0.0f, ui = 0.0f;
            const float* wr = win_r + l * D_SZ * N_SZ;
            const float* wi = win_i + l * D_SZ * N_SZ;
            for (int dd = 0; dd < D_SZ; ++dd) {
                float xr = s_xr[dd], xi = s_xi[dd];
                float ar = wr[dd * N_SZ + n], ai = wi[dd * N_SZ + n];
                ur = fmaf(xr, ar, fmaf(-xi, ai, ur));
                ui = fmaf(xr, ai, fmaf( xi, ar, ui));
            }
            float lam = 1.0f + fabsf(lw[l * N_SZ + n]);
            float th  = t_wrap / lam + lb[l * N_SZ + n];
            float sn  = sinf(th), cs = cosf(th);
            float vr  = ur * cs - ui * sn;
            float vi  = ur * sn + ui * cs;
            vr = vr / (1.0f + expf(-vr));
            vi = vi / (1.0f + expf(-vi));
            s_vr[n] = vr;
            s_vi[n] = vi;
        }
        __syncthreads();

        float yr = 0.0f, yi = 0.0f;
        if (n < D_SZ) {
            const float* orp = wout_r + l * N_SZ * D_SZ;
            const float* oip = wout_i + l * N_SZ * D_SZ;
            for (int j = 0; j < N_SZ; ++j) {
                float vr2 = s_vr[j], vi2 = s_vi[j];
                float br = orp[j * D_SZ + n], bi = oip[j * D_SZ + n];
                yr = fmaf(vr2, br, fmaf(-vi2, bi, yr));
                yi = fmaf(vr2, bi, fmaf( vi2, br, yi));
            }
        }
        __syncthreads();
        if (n < D_SZ) {
            s_xr[n] = yr;
            s_xi[n] = yi;
        }
        __syncthreads();
    }

    if (n < D_SZ) {
        xft[n * B_SZ + b] = make_float2(s_xr[n], s_xi[n]);
    }

#undef FILL
#undef LOADG
#undef COMPG
#undef CONSUME
}

// ---------------------------------------------------------------------------
// Phase 3: out[b][v] = xr[b]@(wr+wi)[:,v] + xi[b]@(wr-wi)[:,v].
// ---------------------------------------------------------------------------
#define VCH 16
__global__ __launch_bounds__(64) void proj_kernel(
    const float2* __restrict__ xft,    // [d][b]
    const float*  __restrict__ owr,    // [D][NSIG]
    const float*  __restrict__ owi,
    float*        __restrict__ out)    // [B][NSIG]
{
    const int v0   = blockIdx.x * VCH;
    const int lane = threadIdx.x;      // = b

    float acc[VCH];
    #pragma unroll
    for (int k = 0; k < VCH; ++k) acc[k] = 0.0f;

    for (int dd = 0; dd < D_SZ; ++dd) {
        float2 x = xft[dd * B_SZ + lane];
        #pragma unroll
        for (int k = 0; k < VCH; ++k) {
            float a = owr[dd * NSIG + v0 + k];
            float c = owi[dd * NSIG + v0 + k];
            acc[k] = fmaf(x.x, a + c, fmaf(x.y, a - c, acc[k]));
        }
    }

    float4* o4 = (float4*)(out + (size_t)lane * NSIG + v0);
    #pragma unroll
    for (int k = 0; k < VCH / 4; ++k) {
        o4[k] = make_float4(acc[4 * k], acc[4 * k + 1],
                            acc[4 * k + 2], acc[4 * k + 3]);
    }
}

// ---------------------------------------------------------------------------
extern "C" void kernel_launch(void* const* d_in, const int* in_sizes, int n_in,
                              void* d_out, int out_size, void* d_ws, size_t ws_size,
                              hipStream_t stream)
{
    const int*   ids    = (const int*)  d_in[0];
    const float* emb    = (const float*)d_in[1];
    const float* win_r  = (const float*)d_in[2];
    const float* win_i  = (const float*)d_in[3];
    const float* wout_r = (const float*)d_in[4];
    const float* wout_i = (const float*)d_in[5];
    const float* lw     = (const float*)d_in[6];
    const float* lb     = (const float*)d_in[7];
    const float* owr    = (const float*)d_in[8];
    const float* owi    = (const float*)d_in[9];
    float*       out    = (float*)d_out;

    float2* xft = (float2*)d_ws;        // 32 KB

    const int nthreads = (PWAVES + 1) * 64;
    scan_fused<<<B_SZ, nthreads, 0, stream>>>(ids, emb, win_r, win_i,
                                              wout_r, wout_i, lw, lb, xft);
    proj_kernel<<<NSIG / VCH, 64, 0, stream>>>(xft, owr, owi, out);
}

// Round 7
// 123.968 us; speedup vs baseline: 3.2705x; 3.2705x over previous
//
#include <hip/hip_runtime.h>
#include <math.h>

#define S_LEN 4096
#define B_SZ  64
#define D_SZ  64
#define N_SZ  128
#define L_SZ  2
#define NSIG  32000

#define TILE   128
#define NT     (S_LEN / TILE)     // 32
#define GRP    16                 // consumer prefetch group
#define PWAVES 4
#define PSTEPS (TILE / PWAVES)    // 32 steps per producer wave per tile

// f32-rounded constants matching jnp.float32(...)
#define PHI_F     1.6180339887498949f
#define TWO_PI_F  6.2831853071795862f
#define INV_PI_F  0.31830988618379067f
#define SQ2_I2PI  0.22507907903927651f   // sqrt(2) / (2*pi)

// ---------------------------------------------------------------------------
// Phase 1: producer/consumer scan (round-5 structure, verbatim).  grid = B
// (64 blocks), block = 320 threads (wave 0 = consumer, waves 1..4 =
// producers).  Producers gather tile t+1 (A, C) pairs into an LDS double
// buffer while the consumer runs the serial chain on tile t.
//
// Scan recurrence (revolutions): q = fma(u, A, C); u = v_sin(q), with
// u = (hr+hi)/sqrt2, q = psi/(2pi) + 1/8, A = sqrt2/(2pi*(1+|w|)),
// C = (b*INV_PI) + t2, t2 = fmodf(t*PHI,2pi)*INV_PI + 0.125.
//
// ROUND-7: single change vs round-5 = transform folded into producers
// (numerics validated by round 6's pass: same rcp, same mul-then-add order;
// NON-volatile asm barrier blocks fma-contraction but not scheduling).
// Round-6's layers-fusion + setprio are REVERTED (they induced scratch
// spill: WRITE_SIZE 32KB -> 6.2MB, 6x regression).
// ---------------------------------------------------------------------------
__global__ __launch_bounds__(PWAVES * 64 + 64, 1) void scan_fused(
    const int*   __restrict__ ids,
    const float* __restrict__ emb,      // raw [V][128]
    float2*      __restrict__ xf)       // [b][d] final (hr,hi)
{
    __shared__ float  s_t2[S_LEN];                // 16 KB: tau/pi + 0.125
    __shared__ float2 sAC[2][TILE][D_SZ];         // 128 KB double buffer

    const int b    = blockIdx.x;
    const int tidx = threadIdx.x;
    const int wv   = tidx >> 6;        // 0 = consumer, 1..4 = producers
    const int lane = tidx & 63;        // = d

    const int* __restrict__ ids_b = ids + b * S_LEN;

    for (int i = tidx; i < S_LEN; i += (PWAVES + 1) * 64)
        s_t2[i] = fmodf((float)i * PHI_F, TWO_PI_F) * INV_PI_F + 0.125f;
    __syncthreads();

// producer: fill strip of tile TLE into buffer BUF (transform folded in;
// values bit-identical to the round-5/6 passing arithmetic)
#define FILL(BUF, TLE) do {                                                  \
    const int t0_ = (TLE) * TILE + (wv - 1) * PSTEPS;                        \
    const int s0_ = (wv - 1) * PSTEPS;                                       \
    _Pragma("unroll")                                                        \
    for (int jj = 0; jj < PSTEPS; ++jj) {                                    \
        int   row_ = ids_b[t0_ + jj] << 7;                                   \
        float t2_  = s_t2[t0_ + jj];                                         \
        float w_   = emb[row_ + lane];                                       \
        float bb_  = emb[row_ + 64 + lane];                                  \
        float A_   = SQ2_I2PI * __builtin_amdgcn_rcpf(1.0f + fabsf(w_));     \
        float bm_  = bb_ * INV_PI_F;                                         \
        asm("" : "+v"(bm_));            /* block fma-contraction only */     \
        float C_   = bm_ + t2_;                                              \
        sAC[BUF][s0_ + jj][lane] = make_float2(A_, C_);                      \
    }                                                                        \
} while (0)

// consumer: 16-step register groups, ping-pong so ds_read latency hides
// under the previous group's fma->v_sin chain
#define LOADG(R, BUF, G) do {                                                \
    _Pragma("unroll")                                                        \
    for (int j = 0; j < GRP; ++j) R[j] = sAC[BUF][(G) * GRP + j][lane];      \
} while (0)

#define COMPG(R) do {                                                        \
    _Pragma("unroll")                                                        \
    for (int j = 0; j < GRP; ++j) {                                          \
        q = fmaf(u, R[j].x, R[j].y);                                         \
        u = __builtin_amdgcn_sinf(q);                                        \
    }                                                                        \
} while (0)

#define CONSUME(BUF) do {                                                    \
    float2 rA[GRP], rB[GRP];                                                 \
    LOADG(rA, BUF, 0);                                                       \
    LOADG(rB, BUF, 1); COMPG(rA);                                            \
    LOADG(rA, BUF, 2); COMPG(rB);                                            \
    LOADG(rB, BUF, 3); COMPG(rA);                                            \
    LOADG(rA, BUF, 4); COMPG(rB);                                            \
    LOADG(rB, BUF, 5); COMPG(rA);                                            \
    LOADG(rA, BUF, 6); COMPG(rB);                                            \
    LOADG(rB, BUF, 7); COMPG(rA);                                            \
    COMPG(rB);                                                               \
} while (0)

    float u = 0.0f, q = 0.0f;

    if (wv > 0) FILL(0, 0);
    __syncthreads();

    for (int t = 0; t < NT; ++t) {
        const int cur = t & 1;
        if (wv > 0) {
            if (t + 1 < NT) FILL(cur ^ 1, t + 1);
        } else {
            CONSUME(cur);
        }
        __syncthreads();
    }

    if (wv == 0) {
        float pr = q - 0.125f;    // = psi_final / (2*pi), revolutions
        xf[b * 64 + lane] = make_float2(__builtin_amdgcn_cosf(pr),
                                        __builtin_amdgcn_sinf(pr));
    }

#undef FILL
#undef LOADG
#undef COMPG
#undef CONSUME
}

// ---------------------------------------------------------------------------
// Phase 2: the two resonant layers at t_last = (S-1)*phi.
// grid = B (64 blocks), block = N (128 threads).
// ---------------------------------------------------------------------------
__global__ __launch_bounds__(128) void layers_kernel(
    const float2* __restrict__ xf,       // [b][d]
    const float*  __restrict__ win_r,    // [L][D][N]
    const float*  __restrict__ win_i,
    const float*  __restrict__ wout_r,   // [L][N][D]
    const float*  __restrict__ wout_i,
    const float*  __restrict__ lw,       // [L][N]
    const float*  __restrict__ lb,
    float2*       __restrict__ xft)      // [d][b] for the projection kernel
{
    const int b = blockIdx.x;
    const int n = threadIdx.x;

    __shared__ float s_xr[D_SZ], s_xi[D_SZ];
    __shared__ float s_vr[N_SZ], s_vi[N_SZ];

    if (n < D_SZ) {
        float2 v = xf[b * D_SZ + n];
        s_xr[n] = v.x;
        s_xi[n] = v.y;
    }
    __syncthreads();

    const float t_last = (float)(4095.0 * 1.618033988749895);
    const float t_wrap = fmodf(t_last, TWO_PI_F);

    for (int l = 0; l < L_SZ; ++l) {
        float ur = 0.0f, ui = 0.0f;
        const float* wr = win_r + l * D_SZ * N_SZ;
        const float* wi = win_i + l * D_SZ * N_SZ;
        for (int dd = 0; dd < D_SZ; ++dd) {
            float xr = s_xr[dd], xi = s_xi[dd];
            float ar = wr[dd * N_SZ + n], ai = wi[dd * N_SZ + n];
            ur = fmaf(xr, ar, fmaf(-xi, ai, ur));
            ui = fmaf(xr, ai, fmaf( xi, ar, ui));
        }
        float lam = 1.0f + fabsf(lw[l * N_SZ + n]);
        float th  = t_wrap / lam + lb[l * N_SZ + n];
        float sn  = sinf(th), cs = cosf(th);
        float vr  = ur * cs - ui * sn;
        float vi  = ur * sn + ui * cs;
        vr = vr / (1.0f + expf(-vr));
        vi = vi / (1.0f + expf(-vi));
        s_vr[n] = vr;
        s_vi[n] = vi;
        __syncthreads();

        float yr = 0.0f, yi = 0.0f;
        if (n < D_SZ) {
            const float* orp = wout_r + l * N_SZ * D_SZ;
            const float* oip = wout_i + l * N_SZ * D_SZ;
            for (int j = 0; j < N_SZ; ++j) {
                float vr2 = s_vr[j], vi2 = s_vi[j];
                float br = orp[j * D_SZ + n], bi = oip[j * D_SZ + n];
                yr = fmaf(vr2, br, fmaf(-vi2, bi, yr));
                yi = fmaf(vr2, bi, fmaf( vi2, br, yi));
            }
        }
        __syncthreads();
        if (n < D_SZ) {
            s_xr[n] = yr;
            s_xi[n] = yi;
        }
        __syncthreads();
    }

    if (n < D_SZ) {
        xft[n * B_SZ + b] = make_float2(s_xr[n], s_xi[n]);
    }
}

// ---------------------------------------------------------------------------
// Phase 3: out[b][v] = xr[b]@(wr+wi)[:,v] + xi[b]@(wr-wi)[:,v].
// ---------------------------------------------------------------------------
#define VCH 16
__global__ __launch_bounds__(64) void proj_kernel(
    const float2* __restrict__ xft,    // [d][b]
    const float*  __restrict__ owr,    // [D][NSIG]
    const float*  __restrict__ owi,
    float*        __restrict__ out)    // [B][NSIG]
{
    const int v0   = blockIdx.x * VCH;
    const int lane = threadIdx.x;      // = b

    float acc[VCH];
    #pragma unroll
    for (int k = 0; k < VCH; ++k) acc[k] = 0.0f;

    for (int dd = 0; dd < D_SZ; ++dd) {
        float2 x = xft[dd * B_SZ + lane];
        #pragma unroll
        for (int k = 0; k < VCH; ++k) {
            float a = owr[dd * NSIG + v0 + k];
            float c = owi[dd * NSIG + v0 + k];
            acc[k] = fmaf(x.x, a + c, fmaf(x.y, a - c, acc[k]));
        }
    }

    float4* o4 = (float4*)(out + (size_t)lane * NSIG + v0);
    #pragma unroll
    for (int k = 0; k < VCH / 4; ++k) {
        o4[k] = make_float4(acc[4 * k], acc[4 * k + 1],
                            acc[4 * k + 2], acc[4 * k + 3]);
    }
}

// ---------------------------------------------------------------------------
extern "C" void kernel_launch(void* const* d_in, const int* in_sizes, int n_in,
                              void* d_out, int out_size, void* d_ws, size_t ws_size,
                              hipStream_t stream)
{
    const int*   ids    = (const int*)  d_in[0];
    const float* emb    = (const float*)d_in[1];
    const float* win_r  = (const float*)d_in[2];
    const float* win_i  = (const float*)d_in[3];
    const float* wout_r = (const float*)d_in[4];
    const float* wout_i = (const float*)d_in[5];
    const float* lw     = (const float*)d_in[6];
    const float* lb     = (const float*)d_in[7];
    const float* owr    = (const float*)d_in[8];
    const float* owi    = (const float*)d_in[9];
    float*       out    = (float*)d_out;

    float2* xf  = (float2*)d_ws;                        // 32 KB
    float2* xft = (float2*)((char*)d_ws + 32 * 1024);   // 32 KB

    const int nthreads = (PWAVES + 1) * 64;
    scan_fused<<<B_SZ, nthreads, 0, stream>>>(ids, emb, xf);
    layers_kernel<<<B_SZ, 128, 0, stream>>>(xf, win_r, win_i, wout_r, wout_i,
                                            lw, lb, xft);
    proj_kernel<<<NSIG / VCH, 64, 0, stream>>>(xft, owr, owi, out);
}